// Round 8
// baseline (103.961 us; speedup 1.0000x reference)
//
#include <hip/hip_runtime.h>

#define N_B    8
#define L_SEQ  2040
#define D_DIM  768
#define KDIM   2304      // 3*768
#define M_ROWS 16320     // N_B*L_SEQ
#define LPAD   2042      // L_SEQ + 2 zero guard rows

typedef __bf16 bf16x8 __attribute__((ext_vector_type(8)));
typedef float  f32x4  __attribute__((ext_vector_type(4)));

__device__ __forceinline__ unsigned short f2bf_u(float f) {
  union { float f; unsigned u; } v; v.f = f;
  unsigned u = v.u;
  return (unsigned short)((u + 0x7FFFu + ((u >> 16) & 1u)) >> 16);
}

__device__ __forceinline__ void async16(const unsigned short* g, const unsigned char* l) {
  __builtin_amdgcn_global_load_lds(
      (const __attribute__((address_space(1))) void*)g,
      (__attribute__((address_space(3))) void*)l, 16, 0, 0);
}

// ---------------- P0: pad + fp32->bf16 convert X ----------------
__global__ void k_pad(const float* __restrict__ X, unsigned short* __restrict__ Xpad) {
  size_t idx = ((size_t)blockIdx.x * 256 + threadIdx.x) * 4;
  const size_t per_n = (size_t)LPAD * D_DIM;
  int n = (int)(idx / per_n);
  size_t rem = idx - (size_t)n * per_n;
  int lp = (int)(rem / D_DIM);
  int d  = (int)(rem - (size_t)lp * D_DIM);
  ushort4 o;
  if (lp == 0 || lp == LPAD - 1) {
    o.x = 0; o.y = 0; o.z = 0; o.w = 0;
  } else {
    const float4 f = *(const float4*)&X[((size_t)n * L_SEQ + (lp - 1)) * D_DIM + d];
    o.x = f2bf_u(f.x); o.y = f2bf_u(f.y); o.z = f2bf_u(f.z); o.w = f2bf_u(f.w);
  }
  *(ushort4*)&Xpad[idx] = o;
}

// ---------------- P1: both weight transposes in one launch (z selects) ----------------
__global__ void k_tr2(const float* __restrict__ wd, unsigned short* __restrict__ wdT,
                      const float* __restrict__ cw, unsigned short* __restrict__ cwT) {
  __shared__ float tile[32][33];
  const int z = blockIdx.z;
  const float* in = z ? cw : wd;
  unsigned short* out = z ? cwT : wdT;
  const int R = 768, C = z ? 2304 : 768;
  if (!z && blockIdx.x >= 24) return;
  int tx = threadIdx.x, ty = threadIdx.y;
  int c0 = blockIdx.x * 32;
  int r0 = blockIdx.y * 32;
  for (int i = ty; i < 32; i += 8) {
    int r = r0 + i, c = c0 + tx;
    tile[i][tx] = (r < R && c < C) ? in[(size_t)r * C + c] : 0.f;
  }
  __syncthreads();
  for (int i = ty; i < 32; i += 8) {
    int oc = c0 + i;
    int orr = r0 + tx;
    if (oc < C && orr < R) out[(size_t)oc * R + orr] = f2bf_u(tile[tx][i]);
  }
}

// ---------------- P2: W2 GEMM -> pre-blocked Bblk (blocks 0..107) + bias2 (108..119) ----
// Bblk element (p,kt,kh,blk,lane=o*16+r,e) = W2[do = p*256+blk*16+r][j = kt*64+kh*32+o*8+e]
// where W2[do][j], j = kk*768+di, is the fused conv*wd weight. Lane-linear: one B image
// (kt) = 32KB contiguous, the exact LDS image k_conv96 stages.
__global__ __launch_bounds__(256) void k_w2b(
    const unsigned short* __restrict__ wdT, const unsigned short* __restrict__ cwT,
    unsigned short* __restrict__ Bblk,
    const float* __restrict__ conv_b, const float* __restrict__ wd,
    const float* __restrict__ bd, float* __restrict__ bias2) {
  __shared__ unsigned short sA[128 * 32];
  __shared__ unsigned short sB[128 * 32];
  __shared__ float red[256];
  const int bid = blockIdx.x;
  const int t = threadIdx.x;

  if (bid >= 108) {   // ---- bias2: 12 blocks, 4 dm-slices per output col ----
    const int b2 = bid - 108;
    const int o = b2 * 64 + (t & 63);
    const int sl = t >> 6;
    float acc = 0.f;
    for (int dm = sl * 192; dm < sl * 192 + 192; ++dm)
      acc += conv_b[dm] * wd[(size_t)dm * D_DIM + o];
    red[t] = acc;
    __syncthreads();
    if (t < 64)
      bias2[o] = 4.f * (red[t] + red[t + 64] + red[t + 128] + red[t + 192]) + bd[o];
    return;
  }

  const int bm = bid / 18, bn = bid - bm * 18;
  const int lane = t & 63, w = t >> 6;
  const int wr = w >> 1, wc = w & 1;
  const int lr = lane & 15, lg = lane >> 4;

  const int c0 = t, c1 = t + 256;
  const unsigned short* aB0 = wdT + (size_t)(bm * 128 + (c0 >> 2)) * 768 + (c0 & 3) * 8;
  const unsigned short* aB1 = wdT + (size_t)(bm * 128 + (c1 >> 2)) * 768 + (c1 & 3) * 8;
  const unsigned short* bB0 = cwT + (size_t)(bn * 128 + (c0 >> 2)) * 768 + (c0 & 3) * 8;
  const unsigned short* bB1 = cwT + (size_t)(bn * 128 + (c1 >> 2)) * 768 + (c1 & 3) * 8;

  f32x4 acc[4][4] = {};
  int aOff[4], bOff[4];
#pragma unroll
  for (int i = 0; i < 4; ++i) {
    aOff[i] = (wr * 64 + i * 16 + lr) * 4 + lg;
    bOff[i] = (wc * 64 + i * 16 + lr) * 4 + lg;
  }
  const bf16x8* At = (const bf16x8*)sA;
  const bf16x8* Bt = (const bf16x8*)sB;

  for (int kt = 0; kt < 24; ++kt) {
    const int ko = kt * 32;
    __syncthreads();
    async16(aB0 + ko, (const unsigned char*)&sA[c0 * 8]);
    async16(aB1 + ko, (const unsigned char*)&sA[c1 * 8]);
    async16(bB0 + ko, (const unsigned char*)&sB[c0 * 8]);
    async16(bB1 + ko, (const unsigned char*)&sB[c1 * 8]);
    __syncthreads();
    bf16x8 av[4], bv[4];
#pragma unroll
    for (int i = 0; i < 4; ++i) { av[i] = At[aOff[i]]; bv[i] = Bt[bOff[i]]; }
#pragma unroll
    for (int mi = 0; mi < 4; ++mi)
#pragma unroll
      for (int ni = 0; ni < 4; ++ni)
        acc[mi][ni] = __builtin_amdgcn_mfma_f32_16x16x32_bf16(av[mi], bv[ni], acc[mi][ni], 0, 0, 0);
  }

#pragma unroll
  for (int ni = 0; ni < 4; ++ni) {
    const int jp = bn * 128 + wc * 64 + ni * 16 + lr;   // j' = di*3+kk
    const int di = jp / 3;
    const int kk = jp - di * 3;
    const int j = kk * 768 + di;                         // GEMM k index
    const int kt2 = j >> 6, rem = j & 63;
    const int kh = rem >> 5, o = (rem >> 3) & 3, e = rem & 7;
    const size_t jbase = (size_t)kt2 * 16384 + kh * 8192 + o * 128 + e;  // + blk*512 + r*8
#pragma unroll
    for (int mi = 0; mi < 4; ++mi) {
      const int row0 = bm * 128 + wr * 64 + mi * 16 + lg * 4;            // do
      f32x4 v = acc[mi][ni];
#pragma unroll
      for (int i = 0; i < 4; ++i) {
        const int dd = row0 + i;
        const int p = dd >> 8, cl = dd & 255, blk = cl >> 4, r = cl & 15;
        Bblk[(size_t)p * 589824 + jbase + blk * 512 + r * 8] = f2bf_u(v[i]);
      }
    }
  }
}

// ---------------- P3: conv-GEMM 96x256 tile, 4 waves, 2 blocks/CU --------------------
// Cross-BLOCK pipe overlap: 2 independent blocks per CU (LDS 76KB each), 1 wave of each
// block per SIMD -> when one block reads/stages/drains, the other feeds the matrix pipe.
// LDS: A single-buf 12KB @0 ([2 kh][6 blk][1024B]); B dbuf 2x32KB @12288/@45056
// ([2 kh][16 blk][1024B]). Blocks are 64 lanes x 16B, lane-linear (conflict-free).
// Per tile: A reads (12) | sched_barrier | B reads (8) | lgkmcnt(8) -> A reads retired
// -> safe to restage A in place | stages (3 A + 8 B) | sched_barrier | MFMAs | syncthreads.
__global__ __launch_bounds__(256, 2) void k_conv96(
    const unsigned short* __restrict__ Xpad, const unsigned short* __restrict__ Bblk,
    const float* __restrict__ bias2, float* __restrict__ Y) {
  __shared__ unsigned char lds[77824];

  const int tid = threadIdx.x;
  const int lane = tid & 63;
  const int wc = tid >> 6;    // wave = n-col slice (4 waves x 64 cols)

  // bijective XCD swizzle for 510 blocks (q=63, r=6)
  const int bid = blockIdx.x;
  const int xcd = bid & 7, idx = bid >> 3;
  const int swz = (xcd < 6 ? xcd * 64 : 384 + (xcd - 6) * 63) + idx;
  const int bm = swz / 3, bn = swz - bm * 3;

  // ---- A staging sources: chunk c = rr*256+tid (768 chunks = 12KB);
  //      kh = c/384, q = c%384, blk = q>>6, li = q&63 -> row = blk*16+(li&15), oct = li>>4
  const unsigned short *aS0, *aS1, *aS2;
  {
#define ACHUNK(rr, dst) { \
    int c = tid + (rr) * 256; \
    int kh = c / 384, q = c - kh * 384; \
    int li = q & 63; \
    int rl = (q >> 6) * 16 + (li & 15); \
    int m = bm * 96 + rl; \
    int n = m / L_SEQ, l = m - n * L_SEQ; \
    dst = Xpad + (size_t)(n * LPAD + l) * D_DIM + kh * 32 + (li >> 4) * 8; }
    ACHUNK(0, aS0) ACHUNK(1, aS1) ACHUNK(2, aS2)
#undef ACHUNK
  }
  // ---- B staging: pre-blocked lane-linear, 32KB per (panel, kt), 8 chunks/thread ----
  const unsigned short* bS = Bblk + (size_t)bn * 589824 + tid * 8;
  const int dA = tid * 16;              // + rr*4096, A buf @0
  const int dB = tid * 16;              // + rr*4096, + buf base

  // ---- ds_read bases ----
  const int aRd = lane * 16;                  // + kh*6144 + mi*1024
  const int bRd = wc * 4096 + lane * 16;      // + bufbase + kh*16384 + ni*1024

  f32x4 acc[6][4] = {};
  bf16x8 avP[6], avQ[6], bvP[4], bvQ[4];

#define STG_A(koff) do { \
    async16(aS0 + (koff), lds + dA); \
    async16(aS1 + (koff), lds + dA + 4096); \
    async16(aS2 + (koff), lds + dA + 8192); } while (0)
#define STG_B(nbB, boff) do { \
    _Pragma("unroll") \
    for (int rr = 0; rr < 8; ++rr) \
      async16(bS + (boff) + rr * 2048, lds + (nbB) + dB + rr * 4096); } while (0)
#define MF24(bA, bB) \
    __builtin_amdgcn_s_setprio(1); \
    _Pragma("unroll") \
    for (int mi = 0; mi < 6; ++mi) \
      _Pragma("unroll") \
      for (int ni = 0; ni < 4; ++ni) \
        acc[mi][ni] = __builtin_amdgcn_mfma_f32_16x16x32_bf16(bA[mi], bB[ni], acc[mi][ni], 0, 0, 0); \
    __builtin_amdgcn_s_setprio(0);

  // prologue: A(t0) + B(t0)->buf0
  STG_A(0);
  STG_B(12288, 0);
  __syncthreads();

  for (int t = 0; t < 36; ++t) {
    const int cbB = 12288 + (t & 1) * 32768;
    const int nbB = 12288 + ((t & 1) ^ 1) * 32768;
    const bool st = (t < 35);
    const int aoff = (t + 1) * 64;                  // A advances along contiguous row-window
    const size_t boff = (size_t)(t + 1) * 16384;    // B image per kt

    // A reads first (order pinned), so lgkmcnt(8) below proves they retired
#pragma unroll
    for (int mi = 0; mi < 6; ++mi)
      avP[mi] = *(const bf16x8*)(lds + aRd + mi * 1024);
#pragma unroll
    for (int mi = 0; mi < 6; ++mi)
      avQ[mi] = *(const bf16x8*)(lds + aRd + 6144 + mi * 1024);
    __builtin_amdgcn_sched_barrier(0);
#pragma unroll
    for (int ni = 0; ni < 4; ++ni)
      bvP[ni] = *(const bf16x8*)(lds + cbB + bRd + ni * 1024);
#pragma unroll
    for (int ni = 0; ni < 4; ++ni)
      bvQ[ni] = *(const bf16x8*)(lds + cbB + bRd + 16384 + ni * 1024);

    if (st) {
      asm volatile("s_waitcnt lgkmcnt(8)" ::: "memory");  // 12 A-reads retired
      STG_A(aoff);               // safe: A buf data already in registers
      STG_B(nbB, boff);          // into the other B buffer
    }
    __builtin_amdgcn_sched_barrier(0);

    MF24(avP, bvP);   // compiler waits lgkmcnt for bvP only; bvQ completes underneath
    MF24(avQ, bvQ);
    __syncthreads();  // drains vmcnt(0): the 11 stages, issued ~1 MFMA-cluster earlier
  }

  // ---- fused pooling epilogue: 2 passes of 48 rows via LDS [48][256] f32 (48KB) ----
  const int lr = lane & 15, lg = lane >> 4;
  const f32x4 bias = *(const f32x4*)&bias2[bn * 256 + lane * 4];
#pragma unroll
  for (int p = 0; p < 2; ++p) {
    if (p) __syncthreads();  // pass-0 reads done before overwrite
#pragma unroll
    for (int mi = 0; mi < 3; ++mi)
#pragma unroll
      for (int ni = 0; ni < 4; ++ni)
#pragma unroll
        for (int i = 0; i < 4; ++i)
          *(float*)(lds + ((mi * 16 + lg * 4 + i) * 256 + (wc * 64 + ni * 16 + lr)) * 4) =
              acc[3 * p + mi][ni][i];
    __syncthreads();
    f32x4 y[12];
#pragma unroll
    for (int i = 0; i < 12; ++i)
      y[i] = *(const f32x4*)(lds + ((wc * 12 + i) * 256 + lane * 4) * 4);
    f32x4 m2[6], m3[4], m4[3];
#pragma unroll
    for (int j = 0; j < 6; ++j) m2[j] = (y[2 * j] + y[2 * j + 1]) * 0.5f;
#pragma unroll
    for (int j = 0; j < 4; ++j) m3[j] = (y[3 * j] + y[3 * j + 1] + y[3 * j + 2]) * (1.f / 3.f);
#pragma unroll
    for (int j = 0; j < 3; ++j) m4[j] = (y[4 * j] + y[4 * j + 1] + y[4 * j + 2] + y[4 * j + 3]) * 0.25f;
    const int grow0 = bm * 96 + p * 48 + wc * 12;
#pragma unroll
    for (int i = 0; i < 12; ++i) {
      f32x4 o = y[i] + m2[i >> 1] + m3[i / 3] + m4[i >> 2] + bias;
      *(f32x4*)&Y[(size_t)(grow0 + i) * D_DIM + bn * 256 + lane * 4] = o;
    }
  }
#undef STG_A
#undef STG_B
#undef MF24
}

// ---------------- launch ----------------
extern "C" void kernel_launch(void* const* d_in, const int* in_sizes, int n_in,
                              void* d_out, int out_size, void* d_ws, size_t ws_size,
                              hipStream_t stream) {
  const float* X      = (const float*)d_in[0];
  const float* conv_w = (const float*)d_in[1];
  const float* conv_b = (const float*)d_in[2];
  // d_in[3] = wr, d_in[4] = br: analytically dead (softmax over size-1 axis == 1)
  const float* wd     = (const float*)d_in[5];
  const float* bd     = (const float*)d_in[6];
  float* out = (float*)d_out;

  const size_t off_Xpad  = 0;          // 8*2042*768 bf16 = 25,092,096 B
  const size_t off_wdT   = 25092096;   // 768*768 bf16
  const size_t off_cwT   = 26271744;   // 2304*768 bf16
  const size_t off_Bblk  = 29810688;   // 3*36*16384 bf16 = 3,538,944 B
  const size_t off_bias2 = 33349632;   // 768 f32
  const size_t NEED      = 33352704;
  if (ws_size < NEED) return;

  char* ws = (char*)d_ws;
  unsigned short* Xpad  = (unsigned short*)(ws + off_Xpad);
  unsigned short* wdT   = (unsigned short*)(ws + off_wdT);
  unsigned short* cwT   = (unsigned short*)(ws + off_cwT);
  unsigned short* Bblk  = (unsigned short*)(ws + off_Bblk);
  float*          bias2 = (float*)(ws + off_bias2);

  k_pad<<<12252, 256, 0, stream>>>(X, Xpad);
  k_tr2<<<dim3(72, 24, 2), dim3(32, 8), 0, stream>>>(wd, wdT, conv_w, cwT);
  k_w2b<<<120, 256, 0, stream>>>(wdT, cwT, Bblk, conv_b, wd, bd, bias2);
  k_conv96<<<510, 256, 0, stream>>>(Xpad, Bblk, bias2, out);
}

// Round 9
// 96.357 us; speedup vs baseline: 1.0789x; 1.0789x over previous
//
#include <hip/hip_runtime.h>

#define N_B    8
#define L_SEQ  2040
#define D_DIM  768
#define KDIM   2304      // 3*768
#define M_ROWS 16320     // N_B*L_SEQ
#define LPAD   2042      // L_SEQ + 2 zero guard rows

typedef __bf16 bf16x8 __attribute__((ext_vector_type(8)));
typedef float  f32x4  __attribute__((ext_vector_type(4)));

__device__ __forceinline__ unsigned short f2bf_u(float f) {
  union { float f; unsigned u; } v; v.f = f;
  unsigned u = v.u;
  return (unsigned short)((u + 0x7FFFu + ((u >> 16) & 1u)) >> 16);
}

__device__ __forceinline__ void async16(const unsigned short* g, const unsigned char* l) {
  __builtin_amdgcn_global_load_lds(
      (const __attribute__((address_space(1))) void*)g,
      (__attribute__((address_space(3))) void*)l, 16, 0, 0);
}

// ---------------- P0+P1 fused: pad/convert X  AND  both weight transposes ----------------
// blocks [0, 12252): pad; blocks [12252, 12252+3456): transpose (x = b%72, y = (b/72)%24,
// z = b/1728). Disjoint inputs/outputs; the small transpose rides along with the
// BW-bound pad instead of serializing in its own launch.
__global__ void k_prep(const float* __restrict__ X, unsigned short* __restrict__ Xpad,
                       const float* __restrict__ wd, unsigned short* __restrict__ wdT,
                       const float* __restrict__ cw, unsigned short* __restrict__ cwT) {
  const int bid = blockIdx.x;
  if (bid < 12252) {
    // ---- pad + fp32->bf16 convert X ----
    size_t idx = ((size_t)bid * 256 + threadIdx.x) * 4;
    const size_t per_n = (size_t)LPAD * D_DIM;
    int n = (int)(idx / per_n);
    size_t rem = idx - (size_t)n * per_n;
    int lp = (int)(rem / D_DIM);
    int d  = (int)(rem - (size_t)lp * D_DIM);
    ushort4 o;
    if (lp == 0 || lp == LPAD - 1) {
      o.x = 0; o.y = 0; o.z = 0; o.w = 0;
    } else {
      const float4 f = *(const float4*)&X[((size_t)n * L_SEQ + (lp - 1)) * D_DIM + d];
      o.x = f2bf_u(f.x); o.y = f2bf_u(f.y); o.z = f2bf_u(f.z); o.w = f2bf_u(f.w);
    }
    *(ushort4*)&Xpad[idx] = o;
    return;
  }
  // ---- transpose: fp32 [R][C] -> bf16 [C][R] ----
  __shared__ float tile[32][33];
  const int b2 = bid - 12252;
  const int bx = b2 % 72, by = (b2 / 72) % 24, z = b2 / 1728;
  const float* in = z ? cw : wd;
  unsigned short* out = z ? cwT : wdT;
  const int R = 768, C = z ? 2304 : 768;
  if (!z && bx >= 24) return;
  const int tx = threadIdx.x & 31, ty = threadIdx.x >> 5;  // 256 thr = 32x8
  const int c0 = bx * 32, r0 = by * 32;
  for (int i = ty; i < 32; i += 8) {
    int r = r0 + i, c = c0 + tx;
    tile[i][tx] = (r < R && c < C) ? in[(size_t)r * C + c] : 0.f;
  }
  __syncthreads();
  for (int i = ty; i < 32; i += 8) {
    int oc = c0 + i;
    int orr = r0 + tx;
    if (oc < C && orr < R) out[(size_t)oc * R + orr] = f2bf_u(tile[tx][i]);
  }
}

// ---------------- P2: W2 GEMM -> pre-blocked Bblk (blocks 0..107) + bias2 (108..119) ----
// Bblk element (p,kt,kh,blk,lane=o*16+r,e) = W2[do = p*256+blk*16+r][j = kt*64+kh*32+o*8+e]
// where W2[do][j], j = kk*768+di, is the fused conv*wd weight. This is the exact LDS image
// the main GEMM stages, so B staging becomes fully-contiguous 1KB per wave-instr.
__global__ __launch_bounds__(256) void k_w2b(
    const unsigned short* __restrict__ wdT, const unsigned short* __restrict__ cwT,
    unsigned short* __restrict__ Bblk,
    const float* __restrict__ conv_b, const float* __restrict__ wd,
    const float* __restrict__ bd, float* __restrict__ bias2) {
  __shared__ unsigned short sA[128 * 32];
  __shared__ unsigned short sB[128 * 32];
  __shared__ float red[256];
  const int bid = blockIdx.x;
  const int t = threadIdx.x;

  if (bid >= 108) {   // ---- bias2: 12 blocks, 4 dm-slices per output col ----
    const int b2 = bid - 108;
    const int o = b2 * 64 + (t & 63);
    const int sl = t >> 6;
    float acc = 0.f;
    for (int dm = sl * 192; dm < sl * 192 + 192; ++dm)
      acc += conv_b[dm] * wd[(size_t)dm * D_DIM + o];
    red[t] = acc;
    __syncthreads();
    if (t < 64)
      bias2[o] = 4.f * (red[t] + red[t + 64] + red[t + 128] + red[t + 192]) + bd[o];
    return;
  }

  const int bm = bid / 18, bn = bid - bm * 18;
  const int lane = t & 63, w = t >> 6;
  const int wr = w >> 1, wc = w & 1;
  const int lr = lane & 15, lg = lane >> 4;

  const int c0 = t, c1 = t + 256;
  const unsigned short* aB0 = wdT + (size_t)(bm * 128 + (c0 >> 2)) * 768 + (c0 & 3) * 8;
  const unsigned short* aB1 = wdT + (size_t)(bm * 128 + (c1 >> 2)) * 768 + (c1 & 3) * 8;
  const unsigned short* bB0 = cwT + (size_t)(bn * 128 + (c0 >> 2)) * 768 + (c0 & 3) * 8;
  const unsigned short* bB1 = cwT + (size_t)(bn * 128 + (c1 >> 2)) * 768 + (c1 & 3) * 8;

  f32x4 acc[4][4] = {};
  int aOff[4], bOff[4];
#pragma unroll
  for (int i = 0; i < 4; ++i) {
    aOff[i] = (wr * 64 + i * 16 + lr) * 4 + lg;
    bOff[i] = (wc * 64 + i * 16 + lr) * 4 + lg;
  }
  const bf16x8* At = (const bf16x8*)sA;
  const bf16x8* Bt = (const bf16x8*)sB;

  for (int kt = 0; kt < 24; ++kt) {
    const int ko = kt * 32;
    __syncthreads();
    async16(aB0 + ko, (const unsigned char*)&sA[c0 * 8]);
    async16(aB1 + ko, (const unsigned char*)&sA[c1 * 8]);
    async16(bB0 + ko, (const unsigned char*)&sB[c0 * 8]);
    async16(bB1 + ko, (const unsigned char*)&sB[c1 * 8]);
    __syncthreads();
    bf16x8 av[4], bv[4];
#pragma unroll
    for (int i = 0; i < 4; ++i) { av[i] = At[aOff[i]]; bv[i] = Bt[bOff[i]]; }
#pragma unroll
    for (int mi = 0; mi < 4; ++mi)
#pragma unroll
      for (int ni = 0; ni < 4; ++ni)
        acc[mi][ni] = __builtin_amdgcn_mfma_f32_16x16x32_bf16(av[mi], bv[ni], acc[mi][ni], 0, 0, 0);
  }

#pragma unroll
  for (int ni = 0; ni < 4; ++ni) {
    const int jp = bn * 128 + wc * 64 + ni * 16 + lr;   // j' = di*3+kk
    const int di = jp / 3;
    const int kk = jp - di * 3;
    const int j = kk * 768 + di;                         // GEMM k index
    const int kt2 = j >> 6, rem = j & 63;
    const int kh = rem >> 5, o = (rem >> 3) & 3, e = rem & 7;
    const size_t jbase = (size_t)kt2 * 16384 + kh * 8192 + o * 128 + e;  // + blk*512 + r*8
#pragma unroll
    for (int mi = 0; mi < 4; ++mi) {
      const int row0 = bm * 128 + wr * 64 + mi * 16 + lg * 4;            // do
      f32x4 v = acc[mi][ni];
#pragma unroll
      for (int i = 0; i < 4; ++i) {
        const int dd = row0 + i;
        const int p = dd >> 8, cl = dd & 255, blk = cl >> 4, r = cl & 15;
        Bblk[(size_t)p * 589824 + jbase + blk * 512 + r * 8] = f2bf_u(v[i]);
      }
    }
  }
}

// ---------------- P3: conv-GEMM 192x256 tile + fused pooling epilogue (round-4 exact) ----
// LDS per buf (56KB): A at +0: [2 kh][12 blk][1024B]; B at +24576: [2 kh][16 blk][1024B].
// Block = 64 lanes x 16B; lane l -> row/col (l&15), k-octet (l>>4). All ds_reads are
// base + l*16 (linear, conflict-free); global_load_lds fills linearly (dst = tid*16).
__global__ __launch_bounds__(512, 2) void k_conv192(
    const unsigned short* __restrict__ Xpad, const unsigned short* __restrict__ Bblk,
    const float* __restrict__ bias2, float* __restrict__ Y) {
  __shared__ unsigned char lds[114688];

  const int tid = threadIdx.x;
  const int lane = tid & 63;
  const int wid = tid >> 6;
  const int wr = wid >> 2, wc = wid & 3;

  // bijective XCD swizzle for 255 blocks (q=31, r=7)
  const int bid = blockIdx.x;
  const int xcd = bid & 7, idx = bid >> 3;
  const int swz = (xcd < 7 ? xcd * 32 : 224 + (xcd - 7) * 31) + idx;
  const int bm = swz / 3, bn = swz - bm * 3;

  // ---- A staging sources: chunk c = rr*512+tid; kh = c/768, q = c%768,
  //      blk = q>>6, li = q&63 -> row = blk*16+(li&15), koct = li>>4 ----
  const unsigned short *aS0, *aS1, *aS2;
  {
#define ACHUNK(rr, dst) { \
    int c = tid + (rr) * 512; \
    int kh = c / 768, q = c - kh * 768; \
    int li = q & 63; \
    int rl = (q >> 6) * 16 + (li & 15); \
    int m = bm * 192 + rl; \
    int n = m / L_SEQ, l = m - n * L_SEQ; \
    dst = Xpad + (size_t)(n * LPAD + l) * D_DIM + kh * 32 + (li >> 4) * 8; }
    ACHUNK(0, aS0) ACHUNK(1, aS1) ACHUNK(2, aS2)
#undef ACHUNK
  }
  // ---- B staging: pre-blocked, purely linear: 32KB per (panel, kt) ----
  const unsigned short* bS = Bblk + (size_t)bn * 589824 + tid * 8;
  const int dA0 = tid * 16, dA1 = dA0 + 8192, dA2 = dA0 + 16384;
  const int dB0 = 24576 + tid * 16, dB1 = dB0 + 8192, dB2 = dB0 + 16384, dB3 = dB0 + 24576;

  // ---- ds_read bases ----
  const int aRd0 = wr * 6144 + lane * 16;            // kh0; +12288 for kh1
  const int bRd0 = 24576 + wc * 4096 + lane * 16;    // kh0; +16384 for kh1

  f32x4 acc[6][4] = {};
  bf16x8 av[6], bv[2];

#define STG(src, koff, dst) async16((src) + (koff), lds + nbb + (dst))
#define LD_AV(kh) \
    _Pragma("unroll") \
    for (int mi = 0; mi < 6; ++mi) \
      av[mi] = *(const bf16x8*)(lds + cb + aRd0 + (kh) * 12288 + mi * 1024);
#define LD_BV(kh, nh) \
    bv[0] = *(const bf16x8*)(lds + cb + bRd0 + (kh) * 16384 + (2 * (nh)) * 1024); \
    bv[1] = *(const bf16x8*)(lds + cb + bRd0 + (kh) * 16384 + (2 * (nh) + 1) * 1024);
#define MF12(nh) \
    __builtin_amdgcn_s_setprio(1); \
    _Pragma("unroll") \
    for (int mi = 0; mi < 6; ++mi) { \
      acc[mi][2 * (nh)]     = __builtin_amdgcn_mfma_f32_16x16x32_bf16(av[mi], bv[0], acc[mi][2 * (nh)], 0, 0, 0); \
      acc[mi][2 * (nh) + 1] = __builtin_amdgcn_mfma_f32_16x16x32_bf16(av[mi], bv[1], acc[mi][2 * (nh) + 1], 0, 0, 0); \
    } \
    __builtin_amdgcn_s_setprio(0);
#define BARR asm volatile("s_barrier" ::: "memory")
#define VM(n) asm volatile("s_waitcnt vmcnt(" #n ")" ::: "memory")
#define LGKM0 asm volatile("s_waitcnt lgkmcnt(0)" ::: "memory")

  // prologue: tile 0 into buf 0, order [A0,A1,B0,B1 | A2,B2,B3]
  {
    const int nbb = 0;
    STG(aS0, 0, dA0); STG(aS1, 0, dA1);
    STG(bS, 0, dB0);  STG(bS, 4096, dB1);
    STG(aS2, 0, dA2);
    STG(bS, 8192, dB2); STG(bS, 12288, dB3);
  }
  VM(3);   // retires A0,A1,B0,B1 -> exactly what q0/q1 read
  BARR;

  for (int t = 0; t < 36; ++t) {
    const int cb = (t & 1) * 57344;
    const int nbb = ((t & 1) ^ 1) * 57344;
    const bool st = (t < 35);
    const int aoff = (t + 1) * 64;          // A: elements along contiguous row-window
    const size_t boff = (size_t)(t + 1) * 16384;  // B: elements per kt image
    // ---- q0: kh0, n-half 0 ----
    LD_AV(0); LD_BV(0, 0);
    if (st) { STG(aS0, aoff, dA0); STG(aS1, aoff, dA1); }
    BARR;
    MF12(0);
    BARR;
    // ---- q1: kh0, n-half 1 ----
    LD_BV(0, 1);
    if (st) { STG(bS, boff, dB0); STG(bS, boff + 4096, dB1); }
    BARR;
    MF12(1);
    if (st) { VM(4); } else { VM(0); }      // retires [A2,B2,B3] of tile t
    BARR;
    // ---- q2: kh1, n-half 0 ----
    LD_AV(1); LD_BV(1, 0);
    if (st) { STG(aS2, aoff, dA2); STG(bS, boff + 8192, dB2); }
    BARR;
    MF12(0);
    BARR;
    // ---- q3: kh1, n-half 1 ----
    LD_BV(1, 1);
    if (st) { STG(bS, boff + 12288, dB3); }
    BARR;
    MF12(1);
    VM(3);                                  // retires [A0,A1,B0,B1] of tile t+1
    BARR;
  }

  // ---- fused pooling epilogue: pass p pools rows [p*96, p*96+96) via LDS [96][256] f32 ----
  const int lr = lane & 15, lg = lane >> 4;
  const f32x4 bias = *(const f32x4*)&bias2[bn * 256 + lane * 4];
#pragma unroll
  for (int p = 0; p < 2; ++p) {
    if (p) { BARR; }  // p=1: pool-reads of p=0 must finish before overwrite
    if (wr == p) {
#pragma unroll
      for (int mi = 0; mi < 6; ++mi)
#pragma unroll
        for (int ni = 0; ni < 4; ++ni)
#pragma unroll
          for (int i = 0; i < 4; ++i)
            *(float*)(lds + ((mi * 16 + lg * 4 + i) * 256 + (wc * 64 + ni * 16 + lr)) * 4) =
                acc[mi][ni][i];
    }
    LGKM0;
    BARR;
    f32x4 y[12];
#pragma unroll
    for (int i = 0; i < 12; ++i)
      y[i] = *(const f32x4*)(lds + ((wid * 12 + i) * 256 + lane * 4) * 4);
    f32x4 m2[6], m3[4], m4[3];
#pragma unroll
    for (int j = 0; j < 6; ++j) m2[j] = (y[2 * j] + y[2 * j + 1]) * 0.5f;
#pragma unroll
    for (int j = 0; j < 4; ++j) m3[j] = (y[3 * j] + y[3 * j + 1] + y[3 * j + 2]) * (1.f / 3.f);
#pragma unroll
    for (int j = 0; j < 3; ++j) m4[j] = (y[4 * j] + y[4 * j + 1] + y[4 * j + 2] + y[4 * j + 3]) * 0.25f;
    const int grow0 = bm * 192 + p * 96 + wid * 12;
#pragma unroll
    for (int i = 0; i < 12; ++i) {
      f32x4 o = y[i] + m2[i >> 1] + m3[i / 3] + m4[i >> 2] + bias;
      *(f32x4*)&Y[(size_t)(grow0 + i) * D_DIM + bn * 256 + lane * 4] = o;
    }
  }
#undef STG
#undef LD_AV
#undef LD_BV
#undef MF12
#undef BARR
#undef VM
#undef LGKM0
}

// ---------------- launch ----------------
extern "C" void kernel_launch(void* const* d_in, const int* in_sizes, int n_in,
                              void* d_out, int out_size, void* d_ws, size_t ws_size,
                              hipStream_t stream) {
  const float* X      = (const float*)d_in[0];
  const float* conv_w = (const float*)d_in[1];
  const float* conv_b = (const float*)d_in[2];
  // d_in[3] = wr, d_in[4] = br: analytically dead (softmax over size-1 axis == 1)
  const float* wd     = (const float*)d_in[5];
  const float* bd     = (const float*)d_in[6];
  float* out = (float*)d_out;

  const size_t off_Xpad  = 0;          // 8*2042*768 bf16 = 25,092,096 B
  const size_t off_wdT   = 25092096;   // 768*768 bf16
  const size_t off_cwT   = 26271744;   // 2304*768 bf16
  const size_t off_Bblk  = 29810688;   // 3*36*16384 bf16 = 3,538,944 B
  const size_t off_bias2 = 33349632;   // 768 f32
  const size_t NEED      = 33352704;
  if (ws_size < NEED) return;

  char* ws = (char*)d_ws;
  unsigned short* Xpad  = (unsigned short*)(ws + off_Xpad);
  unsigned short* wdT   = (unsigned short*)(ws + off_wdT);
  unsigned short* cwT   = (unsigned short*)(ws + off_cwT);
  unsigned short* Bblk  = (unsigned short*)(ws + off_Bblk);
  float*          bias2 = (float*)(ws + off_bias2);

  k_prep<<<12252 + 3456, 256, 0, stream>>>(X, Xpad, wd, wdT, conv_w, cwT);
  k_w2b<<<120, 256, 0, stream>>>(wdT, cwT, Bblk, conv_b, wd, bd, bias2);
  k_conv192<<<255, 512, 0, stream>>>(Xpad, Bblk, bias2, out);
}

// Round 10
// 89.730 us; speedup vs baseline: 1.1586x; 1.0739x over previous
//
#include <hip/hip_runtime.h>

#define N_B    8
#define L_SEQ  2040
#define D_DIM  768
#define KDIM   2304      // 3*768
#define M_ROWS 16320     // N_B*L_SEQ
#define LPAD   2042      // L_SEQ + 2 zero guard rows

typedef __bf16 bf16x8 __attribute__((ext_vector_type(8)));
typedef float  f32x4  __attribute__((ext_vector_type(4)));

__device__ __forceinline__ unsigned short f2bf_u(float f) {
  union { float f; unsigned u; } v; v.f = f;
  unsigned u = v.u;
  return (unsigned short)((u + 0x7FFFu + ((u >> 16) & 1u)) >> 16);
}

__device__ __forceinline__ void async16(const unsigned short* g, const unsigned char* l) {
  __builtin_amdgcn_global_load_lds(
      (const __attribute__((address_space(1))) void*)g,
      (__attribute__((address_space(3))) void*)l, 16, 0, 0);
}

// ---------------- P1: both weight transposes (first launch, ~21 MB) ----------------
__global__ void k_tr2(const float* __restrict__ wd, unsigned short* __restrict__ wdT,
                      const float* __restrict__ cw, unsigned short* __restrict__ cwT) {
  __shared__ float tile[32][33];
  const int z = blockIdx.z;
  const float* in = z ? cw : wd;
  unsigned short* out = z ? cwT : wdT;
  const int R = 768, C = z ? 2304 : 768;
  if (!z && blockIdx.x >= 24) return;
  int tx = threadIdx.x, ty = threadIdx.y;
  int c0 = blockIdx.x * 32;
  int r0 = blockIdx.y * 32;
  for (int i = ty; i < 32; i += 8) {
    int r = r0 + i, c = c0 + tx;
    tile[i][tx] = (r < R && c < C) ? in[(size_t)r * C + c] : 0.f;
  }
  __syncthreads();
  for (int i = ty; i < 32; i += 8) {
    int oc = c0 + i;
    int orr = r0 + tx;
    if (oc < C && orr < R) out[(size_t)oc * R + orr] = f2bf_u(tile[tx][i]);
  }
}

// ---------------- P2+P0 fused: w2b (blocks 0..119) + pad (blocks 120..12371) ----------
// w2b blocks dispatch first (latency-bound, 120 blocks), pad floods the rest of the
// machine (BW-bound) -> w2b hides under pad. Disjoint I/O.
// w2b: Bblk element (p,kt,kh,blk,lane=o*16+r,e) = W2[do=p*256+blk*16+r][j=kt*64+kh*32+o*8+e],
// W2 = wd^T . conv_w-flat; lane-linear, the exact LDS image k_conv192 stages (1KB/wave-instr).
__global__ __launch_bounds__(256) void k_pw(
    const unsigned short* __restrict__ wdT, const unsigned short* __restrict__ cwT,
    unsigned short* __restrict__ Bblk,
    const float* __restrict__ conv_b, const float* __restrict__ wd,
    const float* __restrict__ bd, float* __restrict__ bias2,
    const float* __restrict__ X, unsigned short* __restrict__ Xpad) {
  __shared__ unsigned short sA[128 * 32];
  __shared__ unsigned short sB[128 * 32];
  __shared__ float red[256];
  const int bid = blockIdx.x;
  const int t = threadIdx.x;

  if (bid >= 120) {
    // ---- pad + fp32->bf16 convert X ----
    size_t idx = ((size_t)(bid - 120) * 256 + t) * 4;
    const size_t per_n = (size_t)LPAD * D_DIM;
    int n = (int)(idx / per_n);
    size_t rem = idx - (size_t)n * per_n;
    int lp = (int)(rem / D_DIM);
    int d  = (int)(rem - (size_t)lp * D_DIM);
    ushort4 o;
    if (lp == 0 || lp == LPAD - 1) {
      o.x = 0; o.y = 0; o.z = 0; o.w = 0;
    } else {
      const float4 f = *(const float4*)&X[((size_t)n * L_SEQ + (lp - 1)) * D_DIM + d];
      o.x = f2bf_u(f.x); o.y = f2bf_u(f.y); o.z = f2bf_u(f.z); o.w = f2bf_u(f.w);
    }
    *(ushort4*)&Xpad[idx] = o;
    return;
  }

  if (bid >= 108) {   // ---- bias2: 12 blocks, 4 dm-slices per output col ----
    const int b2 = bid - 108;
    const int o = b2 * 64 + (t & 63);
    const int sl = t >> 6;
    float acc = 0.f;
    for (int dm = sl * 192; dm < sl * 192 + 192; ++dm)
      acc += conv_b[dm] * wd[(size_t)dm * D_DIM + o];
    red[t] = acc;
    __syncthreads();
    if (t < 64)
      bias2[o] = 4.f * (red[t] + red[t + 64] + red[t + 128] + red[t + 192]) + bd[o];
    return;
  }

  // ---- W2 GEMM (blocks 0..107) ----
  const int bm = bid / 18, bn = bid - bm * 18;
  const int lane = t & 63, w = t >> 6;
  const int wr = w >> 1, wc = w & 1;
  const int lr = lane & 15, lg = lane >> 4;

  const int c0 = t, c1 = t + 256;
  const unsigned short* aB0 = wdT + (size_t)(bm * 128 + (c0 >> 2)) * 768 + (c0 & 3) * 8;
  const unsigned short* aB1 = wdT + (size_t)(bm * 128 + (c1 >> 2)) * 768 + (c1 & 3) * 8;
  const unsigned short* bB0 = cwT + (size_t)(bn * 128 + (c0 >> 2)) * 768 + (c0 & 3) * 8;
  const unsigned short* bB1 = cwT + (size_t)(bn * 128 + (c1 >> 2)) * 768 + (c1 & 3) * 8;

  f32x4 acc[4][4] = {};
  int aOff[4], bOff[4];
#pragma unroll
  for (int i = 0; i < 4; ++i) {
    aOff[i] = (wr * 64 + i * 16 + lr) * 4 + lg;
    bOff[i] = (wc * 64 + i * 16 + lr) * 4 + lg;
  }
  const bf16x8* At = (const bf16x8*)sA;
  const bf16x8* Bt = (const bf16x8*)sB;

  for (int kt = 0; kt < 24; ++kt) {
    const int ko = kt * 32;
    __syncthreads();
    async16(aB0 + ko, (const unsigned char*)&sA[c0 * 8]);
    async16(aB1 + ko, (const unsigned char*)&sA[c1 * 8]);
    async16(bB0 + ko, (const unsigned char*)&sB[c0 * 8]);
    async16(bB1 + ko, (const unsigned char*)&sB[c1 * 8]);
    __syncthreads();
    bf16x8 av[4], bv[4];
#pragma unroll
    for (int i = 0; i < 4; ++i) { av[i] = At[aOff[i]]; bv[i] = Bt[bOff[i]]; }
#pragma unroll
    for (int mi = 0; mi < 4; ++mi)
#pragma unroll
      for (int ni = 0; ni < 4; ++ni)
        acc[mi][ni] = __builtin_amdgcn_mfma_f32_16x16x32_bf16(av[mi], bv[ni], acc[mi][ni], 0, 0, 0);
  }

#pragma unroll
  for (int ni = 0; ni < 4; ++ni) {
    const int jp = bn * 128 + wc * 64 + ni * 16 + lr;   // j' = di*3+kk
    const int di = jp / 3;
    const int kk = jp - di * 3;
    const int j = kk * 768 + di;                         // GEMM k index
    const int kt2 = j >> 6, rem = j & 63;
    const int kh = rem >> 5, o = (rem >> 3) & 3, e = rem & 7;
    const size_t jbase = (size_t)kt2 * 16384 + kh * 8192 + o * 128 + e;  // + blk*512 + r*8
#pragma unroll
    for (int mi = 0; mi < 4; ++mi) {
      const int row0 = bm * 128 + wr * 64 + mi * 16 + lg * 4;            // do
      f32x4 v = acc[mi][ni];
#pragma unroll
      for (int i = 0; i < 4; ++i) {
        const int dd = row0 + i;
        const int p = dd >> 8, cl = dd & 255, blk = cl >> 4, r = cl & 15;
        Bblk[(size_t)p * 589824 + jbase + blk * 512 + r * 8] = f2bf_u(v[i]);
      }
    }
  }
}

// ---------------- P3: conv-GEMM 192x256 tile + fused pooling epilogue (round-4 exact) ----
// LDS per buf (56KB): A at +0: [2 kh][12 blk][1024B]; B at +24576: [2 kh][16 blk][1024B].
// Block = 64 lanes x 16B; lane l -> row/col (l&15), k-octet (l>>4). All ds_reads are
// base + l*16 (linear, conflict-free); global_load_lds fills linearly (dst = tid*16).
__global__ __launch_bounds__(512, 2) void k_conv192(
    const unsigned short* __restrict__ Xpad, const unsigned short* __restrict__ Bblk,
    const float* __restrict__ bias2, float* __restrict__ Y) {
  __shared__ unsigned char lds[114688];

  const int tid = threadIdx.x;
  const int lane = tid & 63;
  const int wid = tid >> 6;
  const int wr = wid >> 2, wc = wid & 3;

  // bijective XCD swizzle for 255 blocks (q=31, r=7)
  const int bid = blockIdx.x;
  const int xcd = bid & 7, idx = bid >> 3;
  const int swz = (xcd < 7 ? xcd * 32 : 224 + (xcd - 7) * 31) + idx;
  const int bm = swz / 3, bn = swz - bm * 3;

  // ---- A staging sources: chunk c = rr*512+tid; kh = c/768, q = c%768,
  //      blk = q>>6, li = q&63 -> row = blk*16+(li&15), koct = li>>4 ----
  const unsigned short *aS0, *aS1, *aS2;
  {
#define ACHUNK(rr, dst) { \
    int c = tid + (rr) * 512; \
    int kh = c / 768, q = c - kh * 768; \
    int li = q & 63; \
    int rl = (q >> 6) * 16 + (li & 15); \
    int m = bm * 192 + rl; \
    int n = m / L_SEQ, l = m - n * L_SEQ; \
    dst = Xpad + (size_t)(n * LPAD + l) * D_DIM + kh * 32 + (li >> 4) * 8; }
    ACHUNK(0, aS0) ACHUNK(1, aS1) ACHUNK(2, aS2)
#undef ACHUNK
  }
  // ---- B staging: pre-blocked, purely linear: 32KB per (panel, kt) ----
  const unsigned short* bS = Bblk + (size_t)bn * 589824 + tid * 8;
  const int dA0 = tid * 16, dA1 = dA0 + 8192, dA2 = dA0 + 16384;
  const int dB0 = 24576 + tid * 16, dB1 = dB0 + 8192, dB2 = dB0 + 16384, dB3 = dB0 + 24576;

  // ---- ds_read bases ----
  const int aRd0 = wr * 6144 + lane * 16;            // kh0; +12288 for kh1
  const int bRd0 = 24576 + wc * 4096 + lane * 16;    // kh0; +16384 for kh1

  f32x4 acc[6][4] = {};
  bf16x8 av[6], bv[2];

#define STG(src, koff, dst) async16((src) + (koff), lds + nbb + (dst))
#define LD_AV(kh) \
    _Pragma("unroll") \
    for (int mi = 0; mi < 6; ++mi) \
      av[mi] = *(const bf16x8*)(lds + cb + aRd0 + (kh) * 12288 + mi * 1024);
#define LD_BV(kh, nh) \
    bv[0] = *(const bf16x8*)(lds + cb + bRd0 + (kh) * 16384 + (2 * (nh)) * 1024); \
    bv[1] = *(const bf16x8*)(lds + cb + bRd0 + (kh) * 16384 + (2 * (nh) + 1) * 1024);
#define MF12(nh) \
    __builtin_amdgcn_s_setprio(1); \
    _Pragma("unroll") \
    for (int mi = 0; mi < 6; ++mi) { \
      acc[mi][2 * (nh)]     = __builtin_amdgcn_mfma_f32_16x16x32_bf16(av[mi], bv[0], acc[mi][2 * (nh)], 0, 0, 0); \
      acc[mi][2 * (nh) + 1] = __builtin_amdgcn_mfma_f32_16x16x32_bf16(av[mi], bv[1], acc[mi][2 * (nh) + 1], 0, 0, 0); \
    } \
    __builtin_amdgcn_s_setprio(0);
#define BARR asm volatile("s_barrier" ::: "memory")
#define VM(n) asm volatile("s_waitcnt vmcnt(" #n ")" ::: "memory")
#define LGKM0 asm volatile("s_waitcnt lgkmcnt(0)" ::: "memory")

  // prologue: tile 0 into buf 0, order [A0,A1,B0,B1 | A2,B2,B3]
  {
    const int nbb = 0;
    STG(aS0, 0, dA0); STG(aS1, 0, dA1);
    STG(bS, 0, dB0);  STG(bS, 4096, dB1);
    STG(aS2, 0, dA2);
    STG(bS, 8192, dB2); STG(bS, 12288, dB3);
  }
  VM(3);   // retires A0,A1,B0,B1 -> exactly what q0/q1 read
  BARR;

  for (int t = 0; t < 36; ++t) {
    const int cb = (t & 1) * 57344;
    const int nbb = ((t & 1) ^ 1) * 57344;
    const bool st = (t < 35);
    const int aoff = (t + 1) * 64;          // A: elements along contiguous row-window
    const size_t boff = (size_t)(t + 1) * 16384;  // B: elements per kt image
    // ---- q0: kh0, n-half 0 ----
    LD_AV(0); LD_BV(0, 0);
    if (st) { STG(aS0, aoff, dA0); STG(aS1, aoff, dA1); }
    BARR;
    MF12(0);
    BARR;
    // ---- q1: kh0, n-half 1 ----
    LD_BV(0, 1);
    if (st) { STG(bS, boff, dB0); STG(bS, boff + 4096, dB1); }
    BARR;
    MF12(1);
    if (st) { VM(4); } else { VM(0); }      // retires [A2,B2,B3] of tile t
    BARR;
    // ---- q2: kh1, n-half 0 ----
    LD_AV(1); LD_BV(1, 0);
    if (st) { STG(aS2, aoff, dA2); STG(bS, boff + 8192, dB2); }
    BARR;
    MF12(0);
    BARR;
    // ---- q3: kh1, n-half 1 ----
    LD_BV(1, 1);
    if (st) { STG(bS, boff + 12288, dB3); }
    BARR;
    MF12(1);
    VM(3);                                  // retires [A0,A1,B0,B1] of tile t+1
    BARR;
  }

  // ---- fused pooling epilogue: pass p pools rows [p*96, p*96+96) via LDS [96][256] f32 ----
  const int lr = lane & 15, lg = lane >> 4;
  const f32x4 bias = *(const f32x4*)&bias2[bn * 256 + lane * 4];
#pragma unroll
  for (int p = 0; p < 2; ++p) {
    if (p) { BARR; }  // p=1: pool-reads of p=0 must finish before overwrite
    if (wr == p) {
#pragma unroll
      for (int mi = 0; mi < 6; ++mi)
#pragma unroll
        for (int ni = 0; ni < 4; ++ni)
#pragma unroll
          for (int i = 0; i < 4; ++i)
            *(float*)(lds + ((mi * 16 + lg * 4 + i) * 256 + (wc * 64 + ni * 16 + lr)) * 4) =
                acc[mi][ni][i];
    }
    LGKM0;
    BARR;
    f32x4 y[12];
#pragma unroll
    for (int i = 0; i < 12; ++i)
      y[i] = *(const f32x4*)(lds + ((wid * 12 + i) * 256 + lane * 4) * 4);
    f32x4 m2[6], m3[4], m4[3];
#pragma unroll
    for (int j = 0; j < 6; ++j) m2[j] = (y[2 * j] + y[2 * j + 1]) * 0.5f;
#pragma unroll
    for (int j = 0; j < 4; ++j) m3[j] = (y[3 * j] + y[3 * j + 1] + y[3 * j + 2]) * (1.f / 3.f);
#pragma unroll
    for (int j = 0; j < 3; ++j) m4[j] = (y[4 * j] + y[4 * j + 1] + y[4 * j + 2] + y[4 * j + 3]) * 0.25f;
    const int grow0 = bm * 192 + p * 96 + wid * 12;
#pragma unroll
    for (int i = 0; i < 12; ++i) {
      f32x4 o = y[i] + m2[i >> 1] + m3[i / 3] + m4[i >> 2] + bias;
      *(f32x4*)&Y[(size_t)(grow0 + i) * D_DIM + bn * 256 + lane * 4] = o;
    }
  }
#undef STG
#undef LD_AV
#undef LD_BV
#undef MF12
#undef BARR
#undef VM
#undef LGKM0
}

// ---------------- launch ----------------
extern "C" void kernel_launch(void* const* d_in, const int* in_sizes, int n_in,
                              void* d_out, int out_size, void* d_ws, size_t ws_size,
                              hipStream_t stream) {
  const float* X      = (const float*)d_in[0];
  const float* conv_w = (const float*)d_in[1];
  const float* conv_b = (const float*)d_in[2];
  // d_in[3] = wr, d_in[4] = br: analytically dead (softmax over size-1 axis == 1)
  const float* wd     = (const float*)d_in[5];
  const float* bd     = (const float*)d_in[6];
  float* out = (float*)d_out;

  const size_t off_Xpad  = 0;          // 8*2042*768 bf16 = 25,092,096 B
  const size_t off_wdT   = 25092096;   // 768*768 bf16
  const size_t off_cwT   = 26271744;   // 2304*768 bf16
  const size_t off_Bblk  = 29810688;   // 3*36*16384 bf16 = 3,538,944 B
  const size_t off_bias2 = 33349632;   // 768 f32
  const size_t NEED      = 33352704;
  if (ws_size < NEED) return;

  char* ws = (char*)d_ws;
  unsigned short* Xpad  = (unsigned short*)(ws + off_Xpad);
  unsigned short* wdT   = (unsigned short*)(ws + off_wdT);
  unsigned short* cwT   = (unsigned short*)(ws + off_cwT);
  unsigned short* Bblk  = (unsigned short*)(ws + off_Bblk);
  float*          bias2 = (float*)(ws + off_bias2);

  k_tr2<<<dim3(72, 24, 2), dim3(32, 8), 0, stream>>>(wd, wdT, conv_w, cwT);
  k_pw<<<120 + 12252, 256, 0, stream>>>(wdT, cwT, Bblk, conv_b, wd, bd, bias2, X, Xpad);
  k_conv192<<<255, 512, 0, stream>>>(Xpad, Bblk, bias2, out);
}